// Round 19
// baseline (223.463 us; speedup 1.0000x reference)
//
#include <hip/hip_runtime.h>
#include <cstdint>

#define S_LEN 2048
#define NBATCH 2
#define NHEAD 16
#define E3 3072
#define EDIM 1024
#define DDIM 1024

typedef __attribute__((ext_vector_type(8))) short bf8;
typedef __attribute__((ext_vector_type(4))) float f4;

#define MFMA16(A, B, C) __builtin_amdgcn_mfma_f32_16x16x32_bf16(A, B, C, 0, 0, 0)

__device__ __forceinline__ ushort bf16rn(float f) {
    unsigned u = __builtin_bit_cast(unsigned, f);
    return (ushort)((u + 0x7fffu + ((u >> 16) & 1u)) >> 16);
}

// global -> LDS direct DMA, 16B per lane (linear dest; source pre-swizzled).
__device__ __forceinline__ void gload_lds16(const ushort* g, ushort* l) {
    __builtin_amdgcn_global_load_lds(
        (const __attribute__((address_space(1))) void*)g,
        (__attribute__((address_space(3))) void*)l, 16, 0, 0);
}

// ---------------------------------------------------------------------------
// Merged prep: one launch does x-cast + both weight transposes.
// ---------------------------------------------------------------------------
__global__ __launch_bounds__(256) void prep_all(
    const float* __restrict__ x, ushort* __restrict__ xh,
    const float* __restrict__ Wq, ushort* __restrict__ Tq,
    const float* __restrict__ Wo, ushort* __restrict__ To)
{
    __shared__ float tile[32][33];
    const int t  = threadIdx.x;
    const int id = blockIdx.x;

    if (id < 4096) {                     // x cast: 4096 * 1024 elements
        const int i = (id * 256 + t) * 4;
        float4 v = *(const float4*)&x[i];
        ushort4 h;
        h.x = bf16rn(v.x); h.y = bf16rn(v.y); h.z = bf16rn(v.z); h.w = bf16rn(v.w);
        *(ushort4*)&xh[i] = h;
        return;
    }

    const float* W; ushort* T; int K, N, fid;
    if (id < 4096 + 3072) { W = Wq; T = Tq; K = DDIM; N = E3;   fid = id - 4096; }
    else                  { W = Wo; T = To; K = EDIM; N = DDIM; fid = id - 4096 - 3072; }
    const int n0 = (fid % (N / 32)) << 5;
    const int k0 = (fid / (N / 32)) << 5;
    const int c  = t & 31, r = t >> 5;

    #pragma unroll
    for (int i = 0; i < 4; ++i)
        tile[c][r + (i << 3)] = W[(size_t)(k0 + r + (i << 3)) * N + n0 + c];
    __syncthreads();
    #pragma unroll
    for (int i = 0; i < 4; ++i)
        T[(size_t)(n0 + r + (i << 3)) * K + k0 + c] = bf16rn(tile[r + (i << 3)][c]);
}

// ---------------------------------------------------------------------------
// Plain bf16 MFMA GEMM (r17 form), 128x128 tile, BK=64, 512 thr = 8 waves.
// global_load_lds staging with source-side XOR swizzle; XCD-chunked swizzle.
// MODE 0: C -> bf16 (bias; Q cols (c%192<64) scaled 0.125).
// MODE 1: C -> f32 nontemporal (bias).
// ---------------------------------------------------------------------------
template<int MODE>
__global__ __launch_bounds__(512, 4) void gemm_bf16(
    const ushort* __restrict__ Ah, const ushort* __restrict__ Bh,
    const float* __restrict__ bias,
    float* __restrict__ Cf, ushort* __restrict__ Ch,
    int M, int N, int K)
{
    __shared__ ushort As[128][64];
    __shared__ ushort Bs[128][64];

    const int t    = threadIdx.x;
    const int lane = t & 63;
    const int w    = t >> 6;
    const int lo   = lane & 15, hi = lane >> 4;
    const int wr   = w >> 2;
    const int wc   = w & 3;

    const int nwg  = gridDim.x * gridDim.y;
    const int orig = blockIdx.x + blockIdx.y * gridDim.x;
    const int wgid = (orig & 7) * (nwg >> 3) + (orig >> 3);
    const int rb   = (wgid / gridDim.x) << 7;
    const int cb   = (wgid % gridDim.x) << 7;

    const int lrow = lane >> 3;
    const int scol = ((lane & 7) ^ lrow) << 3;
    const int w8   = w << 1;
    const int rsw  = (lo & 7) << 3;

    f4 acc[4][2] = {};

    for (int k0 = 0; k0 < K; k0 += 64) {
        __syncthreads();
        #pragma unroll
        for (int i = 0; i < 2; ++i) {
            const int r0  = (w8 + i) << 3;
            const int row = r0 + lrow;
            gload_lds16(&Ah[(size_t)(rb + row) * K + k0 + scol], &As[r0][0]);
            gload_lds16(&Bh[(size_t)(cb + row) * K + k0 + scol], &Bs[r0][0]);
        }
        __syncthreads();

        __builtin_amdgcn_s_setprio(1);
        #pragma unroll
        for (int st = 0; st < 2; ++st) {
            const int kc = ((st << 5) + (hi << 3)) ^ rsw;
            bf8 a[4], bfr[2];
            #pragma unroll
            for (int f = 0; f < 4; ++f)
                a[f] = *(const bf8*)&As[(wr << 6) + (f << 4) + lo][kc];
            #pragma unroll
            for (int g = 0; g < 2; ++g)
                bfr[g] = *(const bf8*)&Bs[(wc << 5) + (g << 4) + lo][kc];
            #pragma unroll
            for (int f = 0; f < 4; ++f)
                #pragma unroll
                for (int g = 0; g < 2; ++g)
                    acc[f][g] = MFMA16(a[f], bfr[g], acc[f][g]);
        }
        __builtin_amdgcn_s_setprio(0);
    }

    #pragma unroll
    for (int f = 0; f < 4; ++f) {
        #pragma unroll
        for (int g = 0; g < 2; ++g) {
            const int c  = cb + (wc << 5) + (g << 4) + lo;
            const float bv = bias[c];
            const float qs = (MODE == 0 && (c % 192) < 64) ? 0.125f : 1.0f;
            #pragma unroll
            for (int j = 0; j < 4; ++j) {
                const size_t row = (size_t)rb + (wr << 6) + (f << 4) + (hi << 2) + j;
                float v = (acc[f][g][j] + bv) * qs;
                if constexpr (MODE == 0) {
                    Ch[row * N + c] = bf16rn(v);
                } else {
                    __builtin_nontemporal_store(v, &Cf[row * N + c]);
                }
            }
        }
    }
}

// ---------------------------------------------------------------------------
// Attention kernel A: denominators (r17 form). 1024 thr = 16 waves x 16 q,
// K-tile = 128 keys (16KB LDS). 1-D grid: id = qblk*32 + bh (XCD = bh%8).
// ---------------------------------------------------------------------------
__global__ __launch_bounds__(1024) void attn_denom(
    const ushort* __restrict__ qh, float* __restrict__ sinv)
{
    __shared__ ushort ksh[128][64];

    const int t    = threadIdx.x;
    const int lane = t & 63;
    const int wv   = t >> 6;             // 0..15
    const int lo   = lane & 15, hi = lane >> 4;
    const int bh   = blockIdx.x & 31;
    const int qblk = blockIdx.x >> 5;    // 0..7
    const int b    = bh >> 4, h = bh & 15;
    const size_t base = (size_t)b * S_LEN * E3 + h * 192;
    const int q0   = (qblk << 8) + (wv << 4);

    const int lrow = lane >> 3;
    const int scol = ((lane & 7) ^ lrow) << 3;
    const int r0k  = wv << 3;
    const int rsw  = (lo & 7) << 3;

    bf8 qfh[2];
    #pragma unroll
    for (int st = 0; st < 2; ++st) {
        const size_t off = base + (size_t)(q0 + lo) * E3 + (st << 5) + (hi << 3);
        qfh[st] = *(const bf8*)&qh[off];
    }

    float ssum = 0.0f;
    for (int kt = 0; kt < S_LEN; kt += 128) {
        __syncthreads();
        gload_lds16(&qh[base + 64 + (size_t)(kt + r0k + lrow) * E3 + scol],
                    &ksh[r0k][0]);
        __syncthreads();
        __builtin_amdgcn_s_setprio(1);
        #pragma unroll
        for (int sub = 0; sub < 8; ++sub) {
            f4 acc = {};
            #pragma unroll
            for (int st = 0; st < 2; ++st) {
                const int kc = ((st << 5) + (hi << 3)) ^ rsw;
                bf8 kh = *(const bf8*)&ksh[(sub << 4) + lo][kc];
                acc = MFMA16(kh, qfh[st], acc);
            }
            #pragma unroll
            for (int j = 0; j < 4; ++j) ssum += __expf(acc[j]);
        }
        __builtin_amdgcn_s_setprio(0);
    }
    ssum += __shfl_xor(ssum, 16, 64);
    ssum += __shfl_xor(ssum, 32, 64);
    if (lane < 16)
        sinv[(size_t)bh * S_LEN + q0 + lo] = 1.0f / ssum;
}

// ---------------------------------------------------------------------------
// Attention kernel B: apply, 128-key tiles processed as two wave-private
// 64-key halves per barrier window -> 16 barrier/drain events (was 32) at
// constant traffic, stores, and FP order (bit-exact). 512 thr, 128 q/blk.
// LDS: ksh 16KB + vth 17.4KB + plds 18KB = 51.4KB (2 blocks/CU).
// 1-D grid: id = qblk*32 + bh (XCD = bh%8 for K/V L2 affinity).
// ---------------------------------------------------------------------------
__global__ __launch_bounds__(512) void attn_apply(
    const ushort* __restrict__ qh, const float* __restrict__ sinv,
    float* __restrict__ attn, ushort* __restrict__ oh)
{
    __shared__ ushort ksh[128][64];
    __shared__ ushort vth[64][136];      // V^T: [d][k 0..127, +8 pad]
    __shared__ ushort plds[8][16][72];   // per-wave p (bf16): [q][k-within-64]

    const int t    = threadIdx.x;
    const int lane = t & 63;
    const int wv   = t >> 6;
    const int lo   = lane & 15, hi = lane >> 4;
    const int bh   = blockIdx.x & 31;
    const int qblk = blockIdx.x >> 5;    // 0..15
    const int b    = bh >> 4, h = bh & 15;
    const size_t base = (size_t)b * S_LEN * E3 + h * 192;
    const int q0   = (qblk << 7) + (wv << 4);

    const int lrow = lane >> 3;
    const int scol = ((lane & 7) ^ lrow) << 3;
    const int r0k  = wv << 4;            // each wave stages 16 K-rows (2 gloads)
    const int rsw  = (lo & 7) << 3;
    const int vd   = t & 63;

    bf8 qfh[2];
    #pragma unroll
    for (int st = 0; st < 2; ++st) {
        const size_t off = base + (size_t)(q0 + lo) * E3 + (st << 5) + (hi << 3);
        qfh[st] = *(const bf8*)&qh[off];
    }
    const float inv_s = sinv[(size_t)bh * S_LEN + q0 + lo];

    const int srq = lane >> 4;           // 0..3
    const int srk = (lane & 15) << 2;    // 0..60

    f4 oacc[4] = {};
    for (int kt = 0; kt < S_LEN; kt += 128) {
        __syncthreads();
        #pragma unroll
        for (int i = 0; i < 2; ++i) {    // stage 128 K-rows (16 per wave)
            const int r0 = r0k + (i << 3);
            gload_lds16(&qh[base + 64 + (size_t)(kt + r0 + lrow) * E3 + scol],
                        &ksh[r0][0]);
        }
        #pragma unroll
        for (int i = 0; i < 4; ++i) {    // stage V^T: 128 k-cols per d-row
            const int k4 = ((t >> 6) + (i << 3)) << 2;   // 0..124
            ushort4 v;
            #pragma unroll
            for (int m = 0; m < 4; ++m)
                ((ushort*)&v)[m] = qh[base + 128 + (size_t)(kt + k4 + m) * E3 + vd];
            *(ushort4*)&vth[vd][k4] = v;
        }
        __syncthreads();

        #pragma unroll
        for (int half = 0; half < 2; ++half) {
            const int koff = half << 6;

            // QK^T + softmax-apply -> plds (bf16), keys kt+koff .. +63
            #pragma unroll
            for (int sub = 0; sub < 4; ++sub) {
                f4 acc = {};
                __builtin_amdgcn_s_setprio(1);
                #pragma unroll
                for (int st = 0; st < 2; ++st) {
                    const int kc = ((st << 5) + (hi << 3)) ^ rsw;
                    bf8 kh = *(const bf8*)&ksh[koff + (sub << 4) + lo][kc];
                    acc = MFMA16(kh, qfh[st], acc);
                }
                __builtin_amdgcn_s_setprio(0);
                float p0 = __expf(acc[0]) * inv_s;
                float p1 = __expf(acc[1]) * inv_s;
                float p2 = __expf(acc[2]) * inv_s;
                float p3 = __expf(acc[3]) * inv_s;
                unsigned pk0, pk1;
                asm("v_cvt_pk_bf16_f32 %0, %1, %2" : "=v"(pk0) : "v"(p0), "v"(p1));
                asm("v_cvt_pk_bf16_f32 %0, %1, %2" : "=v"(pk1) : "v"(p2), "v"(p3));
                unsigned* pd = (unsigned*)&plds[wv][lo][(sub << 4) + (hi << 2)];
                pd[0] = pk0; pd[1] = pk1;
            }
            // PV: o += p @ V (V columns koff..koff+63)
            __builtin_amdgcn_s_setprio(1);
            #pragma unroll
            for (int kk = 0; kk < 2; ++kk) {
                bf8 pa = *(const bf8*)&plds[wv][lo][(kk << 5) + (hi << 3)];
                #pragma unroll
                for (int dt = 0; dt < 4; ++dt) {
                    bf8 vb = *(const bf8*)&vth[(dt << 4) + lo][koff + (kk << 5) + (hi << 3)];
                    oacc[dt] = MFMA16(pa, vb, oacc[dt]);
                }
            }
            __builtin_amdgcn_s_setprio(0);

            // coalesced attention store: 4 rows x 256B full lines per instr
            #pragma unroll
            for (int i = 0; i < 4; ++i) {
                const int qr = (i << 2) + srq;
                ushort4 pv4 = *(const ushort4*)&plds[wv][qr][srk];
                f4 pw;
                pw[0] = __builtin_bit_cast(float, (unsigned)pv4.x << 16);
                pw[1] = __builtin_bit_cast(float, (unsigned)pv4.y << 16);
                pw[2] = __builtin_bit_cast(float, (unsigned)pv4.z << 16);
                pw[3] = __builtin_bit_cast(float, (unsigned)pv4.w << 16);
                __builtin_nontemporal_store(pw,
                    (f4*)&attn[((size_t)bh * S_LEN + q0 + qr) * S_LEN +
                               kt + koff + srk]);
            }
        }
    }

    // epilogue: o head -> bf16
    #pragma unroll
    for (int dt = 0; dt < 4; ++dt) {
        #pragma unroll
        for (int j = 0; j < 4; ++j) {
            const size_t row = (size_t)b * S_LEN + q0 + (hi << 2) + j;
            oh[row * EDIM + h * 64 + (dt << 4) + lo] = bf16rn(oacc[dt][j]);
        }
    }
}

// ---------------------------------------------------------------------------
extern "C" void kernel_launch(void* const* d_in, const int* in_sizes, int n_in,
                              void* d_out, int out_size, void* d_ws, size_t ws_size,
                              hipStream_t stream)
{
    const float* x    = (const float*)d_in[0];
    const float* Wqkv = (const float*)d_in[1];
    const float* bqkv = (const float*)d_in[2];
    const float* Wout = (const float*)d_in[3];
    const float* bout = (const float*)d_in[4];

    float* o_out    = (float*)d_out;
    float* attn_out = o_out + (size_t)NBATCH * S_LEN * DDIM;

    const size_t nQKV = (size_t)NBATCH * S_LEN * E3;
    const size_t nO   = (size_t)NBATCH * S_LEN * EDIM;
    const size_t nWq  = (size_t)DDIM * E3;
    const size_t nWo  = (size_t)EDIM * DDIM;

    ushort* qh    = (ushort*)d_ws;        // qkv bf16
    ushort* oh    = qh + nQKV;            // o-head bf16 (xh overlay before attn)
    ushort* wqt_h = oh + nO;
    ushort* wot_h = wqt_h + nWq;
    float*  sinv  = (float*)(wot_h + nWo);   // [32][2048] inverse denominators

    ushort* xh = oh;   // x bf16, dead after gemm1

    const int M = NBATCH * S_LEN;  // 4096

    // P: x cast + both weight transposes, one launch
    prep_all<<<4096 + 3072 + 1024, 256, 0, stream>>>(
        x, xh, Wqkv, wqt_h, Wout, wot_h);

    // K1: qkv = x @ Wqkv + bqkv (bf16, Q pre-scaled 0.125)
    gemm_bf16<0><<<dim3(E3 / 128, M / 128), 512, 0, stream>>>(
        xh, wqt_h, bqkv, nullptr, qh, M, E3, DDIM);

    // K2a: softmax denominators (256 q/block, 128-key tiles)
    attn_denom<<<(S_LEN / 256) * NBATCH * NHEAD, 1024, 0, stream>>>(qh, sinv);

    // K2b: attention write + PV (128-key tiles, half the barrier events)
    attn_apply<<<(S_LEN / 128) * NBATCH * NHEAD, 512, 0, stream>>>(
        qh, sinv, attn_out, oh);

    // K3: o = o_head @ Wout + bout (bf16, f32 out)
    gemm_bf16<1><<<dim3(DDIM / 128, M / 128), 512, 0, stream>>>(
        oh, wot_h, bout, o_out, nullptr, M, DDIM, EDIM);
}

// Round 20
// 211.976 us; speedup vs baseline: 1.0542x; 1.0542x over previous
//
#include <hip/hip_runtime.h>
#include <cstdint>

#define S_LEN 2048
#define NBATCH 2
#define NHEAD 16
#define E3 3072
#define EDIM 1024
#define DDIM 1024

typedef __attribute__((ext_vector_type(8))) short bf8;
typedef __attribute__((ext_vector_type(4))) float f4;

#define MFMA16(A, B, C) __builtin_amdgcn_mfma_f32_16x16x32_bf16(A, B, C, 0, 0, 0)

__device__ __forceinline__ ushort bf16rn(float f) {
    unsigned u = __builtin_bit_cast(unsigned, f);
    return (ushort)((u + 0x7fffu + ((u >> 16) & 1u)) >> 16);
}

// global -> LDS direct DMA, 16B per lane (linear dest; source pre-swizzled).
__device__ __forceinline__ void gload_lds16(const ushort* g, ushort* l) {
    __builtin_amdgcn_global_load_lds(
        (const __attribute__((address_space(1))) void*)g,
        (__attribute__((address_space(3))) void*)l, 16, 0, 0);
}

// ---------------------------------------------------------------------------
// Merged prep: one launch does x-cast + both weight transposes.
// ---------------------------------------------------------------------------
__global__ __launch_bounds__(256) void prep_all(
    const float* __restrict__ x, ushort* __restrict__ xh,
    const float* __restrict__ Wq, ushort* __restrict__ Tq,
    const float* __restrict__ Wo, ushort* __restrict__ To)
{
    __shared__ float tile[32][33];
    const int t  = threadIdx.x;
    const int id = blockIdx.x;

    if (id < 4096) {                     // x cast: 4096 * 1024 elements
        const int i = (id * 256 + t) * 4;
        float4 v = *(const float4*)&x[i];
        ushort4 h;
        h.x = bf16rn(v.x); h.y = bf16rn(v.y); h.z = bf16rn(v.z); h.w = bf16rn(v.w);
        *(ushort4*)&xh[i] = h;
        return;
    }

    const float* W; ushort* T; int K, N, fid;
    if (id < 4096 + 3072) { W = Wq; T = Tq; K = DDIM; N = E3;   fid = id - 4096; }
    else                  { W = Wo; T = To; K = EDIM; N = DDIM; fid = id - 4096 - 3072; }
    const int n0 = (fid % (N / 32)) << 5;
    const int k0 = (fid / (N / 32)) << 5;
    const int c  = t & 31, r = t >> 5;

    #pragma unroll
    for (int i = 0; i < 4; ++i)
        tile[c][r + (i << 3)] = W[(size_t)(k0 + r + (i << 3)) * N + n0 + c];
    __syncthreads();
    #pragma unroll
    for (int i = 0; i < 4; ++i)
        T[(size_t)(n0 + r + (i << 3)) * K + k0 + c] = bf16rn(tile[r + (i << 3)][c]);
}

// ---------------------------------------------------------------------------
// Plain bf16 MFMA GEMM, 128x128 tile, BK=64, 512 thr = 8 waves (2x4 of 64x32).
// global_load_lds staging with source-side XOR swizzle; XCD-chunked swizzle.
// MODE 0: C -> bf16 (bias; Q cols (c%192<64) scaled 0.125).
// MODE 1: C -> f32 nontemporal (bias).
// ---------------------------------------------------------------------------
template<int MODE>
__global__ __launch_bounds__(512, 4) void gemm_bf16(
    const ushort* __restrict__ Ah, const ushort* __restrict__ Bh,
    const float* __restrict__ bias,
    float* __restrict__ Cf, ushort* __restrict__ Ch,
    int M, int N, int K)
{
    __shared__ ushort As[128][64];
    __shared__ ushort Bs[128][64];

    const int t    = threadIdx.x;
    const int lane = t & 63;
    const int w    = t >> 6;
    const int lo   = lane & 15, hi = lane >> 4;
    const int wr   = w >> 2;
    const int wc   = w & 3;

    const int nwg  = gridDim.x * gridDim.y;
    const int orig = blockIdx.x + blockIdx.y * gridDim.x;
    const int wgid = (orig & 7) * (nwg >> 3) + (orig >> 3);
    const int rb   = (wgid / gridDim.x) << 7;
    const int cb   = (wgid % gridDim.x) << 7;

    const int lrow = lane >> 3;
    const int scol = ((lane & 7) ^ lrow) << 3;
    const int w8   = w << 1;
    const int rsw  = (lo & 7) << 3;

    f4 acc[4][2] = {};

    for (int k0 = 0; k0 < K; k0 += 64) {
        __syncthreads();
        #pragma unroll
        for (int i = 0; i < 2; ++i) {
            const int r0  = (w8 + i) << 3;
            const int row = r0 + lrow;
            gload_lds16(&Ah[(size_t)(rb + row) * K + k0 + scol], &As[r0][0]);
            gload_lds16(&Bh[(size_t)(cb + row) * K + k0 + scol], &Bs[r0][0]);
        }
        __syncthreads();

        __builtin_amdgcn_s_setprio(1);
        #pragma unroll
        for (int st = 0; st < 2; ++st) {
            const int kc = ((st << 5) + (hi << 3)) ^ rsw;
            bf8 a[4], bfr[2];
            #pragma unroll
            for (int f = 0; f < 4; ++f)
                a[f] = *(const bf8*)&As[(wr << 6) + (f << 4) + lo][kc];
            #pragma unroll
            for (int g = 0; g < 2; ++g)
                bfr[g] = *(const bf8*)&Bs[(wc << 5) + (g << 4) + lo][kc];
            #pragma unroll
            for (int f = 0; f < 4; ++f)
                #pragma unroll
                for (int g = 0; g < 2; ++g)
                    acc[f][g] = MFMA16(a[f], bfr[g], acc[f][g]);
        }
        __builtin_amdgcn_s_setprio(0);
    }

    #pragma unroll
    for (int f = 0; f < 4; ++f) {
        #pragma unroll
        for (int g = 0; g < 2; ++g) {
            const int c  = cb + (wc << 5) + (g << 4) + lo;
            const float bv = bias[c];
            const float qs = (MODE == 0 && (c % 192) < 64) ? 0.125f : 1.0f;
            #pragma unroll
            for (int j = 0; j < 4; ++j) {
                const size_t row = (size_t)rb + (wr << 6) + (f << 4) + (hi << 2) + j;
                float v = (acc[f][g][j] + bv) * qs;
                if constexpr (MODE == 0) {
                    Ch[row * N + c] = bf16rn(v);
                } else {
                    __builtin_nontemporal_store(v, &Cf[row * N + c]);
                }
            }
        }
    }
}

// ---------------------------------------------------------------------------
// Attention kernel A: denominators. 1024 thr = 16 waves x 16 q = 256 q/blk,
// K-tile = 128 keys (16KB LDS). 1-D grid: id = qblk*32 + bh (XCD = bh%8).
// ---------------------------------------------------------------------------
__global__ __launch_bounds__(1024) void attn_denom(
    const ushort* __restrict__ qh, float* __restrict__ sinv)
{
    __shared__ ushort ksh[128][64];

    const int t    = threadIdx.x;
    const int lane = t & 63;
    const int wv   = t >> 6;             // 0..15
    const int lo   = lane & 15, hi = lane >> 4;
    const int bh   = blockIdx.x & 31;
    const int qblk = blockIdx.x >> 5;    // 0..7
    const int b    = bh >> 4, h = bh & 15;
    const size_t base = (size_t)b * S_LEN * E3 + h * 192;
    const int q0   = (qblk << 8) + (wv << 4);

    const int lrow = lane >> 3;
    const int scol = ((lane & 7) ^ lrow) << 3;
    const int r0k  = wv << 3;
    const int rsw  = (lo & 7) << 3;

    bf8 qfh[2];
    #pragma unroll
    for (int st = 0; st < 2; ++st) {
        const size_t off = base + (size_t)(q0 + lo) * E3 + (st << 5) + (hi << 3);
        qfh[st] = *(const bf8*)&qh[off];
    }

    float ssum = 0.0f;
    for (int kt = 0; kt < S_LEN; kt += 128) {
        __syncthreads();
        gload_lds16(&qh[base + 64 + (size_t)(kt + r0k + lrow) * E3 + scol],
                    &ksh[r0k][0]);
        __syncthreads();
        __builtin_amdgcn_s_setprio(1);
        #pragma unroll
        for (int sub = 0; sub < 8; ++sub) {
            f4 acc = {};
            #pragma unroll
            for (int st = 0; st < 2; ++st) {
                const int kc = ((st << 5) + (hi << 3)) ^ rsw;
                bf8 kh = *(const bf8*)&ksh[(sub << 4) + lo][kc];
                acc = MFMA16(kh, qfh[st], acc);
            }
            #pragma unroll
            for (int j = 0; j < 4; ++j) ssum += __expf(acc[j]);
        }
        __builtin_amdgcn_s_setprio(0);
    }
    ssum += __shfl_xor(ssum, 16, 64);
    ssum += __shfl_xor(ssum, 32, 64);
    if (lane < 16)
        sinv[(size_t)bh * S_LEN + q0 + lo] = 1.0f / ssum;
}

// ---------------------------------------------------------------------------
// Attention kernel B: apply (r17 form). 512 thr, 128 q/blk, 64-key tiles,
// 35.2KB LDS -> 4 blocks/CU. Full-line coalesced nontemporal attn stores.
// 1-D grid: id = qblk*32 + bh (XCD = bh%8 for K/V L2 affinity).
// ---------------------------------------------------------------------------
__global__ __launch_bounds__(512) void attn_apply(
    const ushort* __restrict__ qh, const float* __restrict__ sinv,
    float* __restrict__ attn, ushort* __restrict__ oh)
{
    __shared__ ushort ksh[64][64];
    __shared__ ushort vth[64][72];       // V^T: [d][k]
    __shared__ ushort plds[8][16][72];   // per-wave p (bf16): [q][k]

    const int t    = threadIdx.x;
    const int lane = t & 63;
    const int wv   = t >> 6;
    const int lo   = lane & 15, hi = lane >> 4;
    const int bh   = blockIdx.x & 31;
    const int qblk = blockIdx.x >> 5;    // 0..15
    const int b    = bh >> 4, h = bh & 15;
    const size_t base = (size_t)b * S_LEN * E3 + h * 192;
    const int q0   = (qblk << 7) + (wv << 4);

    const int lrow = lane >> 3;
    const int scol = ((lane & 7) ^ lrow) << 3;
    const int r0k  = wv << 3;
    const int rsw  = (lo & 7) << 3;
    const int vd   = t & 63;

    bf8 qfh[2];
    #pragma unroll
    for (int st = 0; st < 2; ++st) {
        const size_t off = base + (size_t)(q0 + lo) * E3 + (st << 5) + (hi << 3);
        qfh[st] = *(const bf8*)&qh[off];
    }
    const float inv_s = sinv[(size_t)bh * S_LEN + q0 + lo];

    const int srq = lane >> 4;           // 0..3
    const int srk = (lane & 15) << 2;    // 0..60

    f4 oacc[4] = {};
    for (int kt = 0; kt < S_LEN; kt += 64) {
        __syncthreads();
        gload_lds16(&qh[base + 64 + (size_t)(kt + r0k + lrow) * E3 + scol],
                    &ksh[r0k][0]);
        #pragma unroll
        for (int i = 0; i < 2; ++i) {   // stage V^T (row-coalesced reads)
            const int k4 = ((t >> 6) + (i << 3)) << 2;
            ushort4 v;
            #pragma unroll
            for (int m = 0; m < 4; ++m)
                ((ushort*)&v)[m] = qh[base + 128 + (size_t)(kt + k4 + m) * E3 + vd];
            *(ushort4*)&vth[vd][k4] = v;
        }
        __syncthreads();

        // QK^T + softmax-apply -> plds (bf16)
        #pragma unroll
        for (int sub = 0; sub < 4; ++sub) {
            f4 acc = {};
            __builtin_amdgcn_s_setprio(1);
            #pragma unroll
            for (int st = 0; st < 2; ++st) {
                const int kc = ((st << 5) + (hi << 3)) ^ rsw;
                bf8 kh = *(const bf8*)&ksh[(sub << 4) + lo][kc];
                acc = MFMA16(kh, qfh[st], acc);
            }
            __builtin_amdgcn_s_setprio(0);
            float p0 = __expf(acc[0]) * inv_s;
            float p1 = __expf(acc[1]) * inv_s;
            float p2 = __expf(acc[2]) * inv_s;
            float p3 = __expf(acc[3]) * inv_s;
            unsigned pk0, pk1;
            asm("v_cvt_pk_bf16_f32 %0, %1, %2" : "=v"(pk0) : "v"(p0), "v"(p1));
            asm("v_cvt_pk_bf16_f32 %0, %1, %2" : "=v"(pk1) : "v"(p2), "v"(p3));
            unsigned* pd = (unsigned*)&plds[wv][lo][(sub << 4) + (hi << 2)];
            pd[0] = pk0; pd[1] = pk1;
        }
        // PV: o += p @ V
        __builtin_amdgcn_s_setprio(1);
        #pragma unroll
        for (int kk = 0; kk < 2; ++kk) {
            bf8 pa = *(const bf8*)&plds[wv][lo][(kk << 5) + (hi << 3)];
            #pragma unroll
            for (int dt = 0; dt < 4; ++dt) {
                bf8 vb = *(const bf8*)&vth[(dt << 4) + lo][(kk << 5) + (hi << 3)];
                oacc[dt] = MFMA16(pa, vb, oacc[dt]);
            }
        }
        __builtin_amdgcn_s_setprio(0);

        // coalesced attention store: instr i writes 4 rows x 256B full lines
        #pragma unroll
        for (int i = 0; i < 4; ++i) {
            const int qr = (i << 2) + srq;
            ushort4 pv4 = *(const ushort4*)&plds[wv][qr][srk];
            f4 pw;
            pw[0] = __builtin_bit_cast(float, (unsigned)pv4.x << 16);
            pw[1] = __builtin_bit_cast(float, (unsigned)pv4.y << 16);
            pw[2] = __builtin_bit_cast(float, (unsigned)pv4.z << 16);
            pw[3] = __builtin_bit_cast(float, (unsigned)pv4.w << 16);
            __builtin_nontemporal_store(pw,
                (f4*)&attn[((size_t)bh * S_LEN + q0 + qr) * S_LEN + kt + srk]);
        }
    }

    // epilogue: o head -> bf16
    #pragma unroll
    for (int dt = 0; dt < 4; ++dt) {
        #pragma unroll
        for (int j = 0; j < 4; ++j) {
            const size_t row = (size_t)b * S_LEN + q0 + (hi << 2) + j;
            oh[row * EDIM + h * 64 + (dt << 4) + lo] = bf16rn(oacc[dt][j]);
        }
    }
}

// ---------------------------------------------------------------------------
extern "C" void kernel_launch(void* const* d_in, const int* in_sizes, int n_in,
                              void* d_out, int out_size, void* d_ws, size_t ws_size,
                              hipStream_t stream)
{
    const float* x    = (const float*)d_in[0];
    const float* Wqkv = (const float*)d_in[1];
    const float* bqkv = (const float*)d_in[2];
    const float* Wout = (const float*)d_in[3];
    const float* bout = (const float*)d_in[4];

    float* o_out    = (float*)d_out;
    float* attn_out = o_out + (size_t)NBATCH * S_LEN * DDIM;

    const size_t nQKV = (size_t)NBATCH * S_LEN * E3;
    const size_t nO   = (size_t)NBATCH * S_LEN * EDIM;
    const size_t nWq  = (size_t)DDIM * E3;
    const size_t nWo  = (size_t)EDIM * DDIM;

    ushort* qh    = (ushort*)d_ws;        // qkv bf16
    ushort* oh    = qh + nQKV;            // o-head bf16 (xh overlay before attn)
    ushort* wqt_h = oh + nO;
    ushort* wot_h = wqt_h + nWq;
    float*  sinv  = (float*)(wot_h + nWo);   // [32][2048] inverse denominators

    ushort* xh = oh;   // x bf16, dead after gemm1

    const int M = NBATCH * S_LEN;  // 4096

    // P: x cast + both weight transposes, one launch
    prep_all<<<4096 + 3072 + 1024, 256, 0, stream>>>(
        x, xh, Wqkv, wqt_h, Wout, wot_h);

    // K1: qkv = x @ Wqkv + bqkv (bf16, Q pre-scaled 0.125)
    gemm_bf16<0><<<dim3(E3 / 128, M / 128), 512, 0, stream>>>(
        xh, wqt_h, bqkv, nullptr, qh, M, E3, DDIM);

    // K2a: softmax denominators (256 q/block, 128-key tiles)
    attn_denom<<<(S_LEN / 256) * NBATCH * NHEAD, 1024, 0, stream>>>(qh, sinv);

    // K2b: attention write + PV
    attn_apply<<<(S_LEN / 128) * NBATCH * NHEAD, 512, 0, stream>>>(
        qh, sinv, attn_out, oh);

    // K3: o = o_head @ Wout + bout (bf16, f32 out)
    gemm_bf16<1><<<dim3(DDIM / 128, M / 128), 512, 0, stream>>>(
        oh, wot_h, bout, o_out, nullptr, M, DDIM, EDIM);
}